// Round 1
// baseline (254.315 us; speedup 1.0000x reference)
//
#include <hip/hip_runtime.h>

// VTM downsampler, scale factor 2.0, fused separable 6-tap (only phases 0/4/8/12
// of the 16-phase table are reachable, and they are zero outside taps 3..8).
//
// Exactness: inputs are integer-valued fp32 in [0,255]; all coefficients are
// integers; every partial sum is bounded by 255*184*184 < 2^24, so fp32 math is
// exact integer arithmetic => pass order commutes and trunc() is the identity.
// Final (acc+8192)*2^-14 is an exact scale by a power of two; floorf matches
// jnp.floor bit-exactly.

#define H_IN   1080
#define W_IN   1920
#define H_OUT  540
#define W_OUT  960
#define N_BC   24   // 8 batches * 3 channels

__global__ __launch_bounds__(256)
void vtm_down_kernel(const float* __restrict__ x, float* __restrict__ out)
{
    const int tx = blockIdx.x * 64 + threadIdx.x;       // float4 column index [0, 240)
    if (tx >= W_OUT / 4) return;
    const int yo = blockIdx.y * 4 + threadIdx.y;        // output row [0, 540)
    const int bc = blockIdx.z;                          // fused batch*channel

    const int xi = tx;            // input center column = (4*tx + p) >> 2
    const int yi = yo >> 2;
    const int yp = yo & 3;        // wave-uniform (blockDim.x == 64)

    // Phase coefficient rows (tap offsets -2..+3):
    //  p=0 (frac 0):  {0,0,128,0,0,0}
    //  p=1 (frac 4):  {5,-18,114,36,-10,1}
    //  p=2 (frac 8):  {4,-19,79,79,-19,4}
    //  p=3 (frac 12): {1,-10,36,114,-18,5}
    const float P0[6] = {0.f, 0.f, 128.f, 0.f, 0.f, 0.f};
    const float P1[6] = {5.f, -18.f, 114.f, 36.f, -10.f, 1.f};
    const float P2[6] = {4.f, -19.f, 79.f, 79.f, -19.f, 4.f};
    const float P3[6] = {1.f, -10.f, 36.f, 114.f, -18.f, 5.f};

    const float* __restrict__ xb = x + (size_t)bc * (H_IN * W_IN);

    // Vertical pass first (shared by the 4 horizontal phases).
    float v[6] = {0.f, 0.f, 0.f, 0.f, 0.f, 0.f};
    #pragma unroll
    for (int s = 0; s < 6; ++s) {
        int r = yi - 2 + s;
        r = r < 0 ? 0 : r;                 // upper edge never reached (yi <= 134)
        const float cys = (yp == 0) ? P0[s] : (yp == 1) ? P1[s]
                        : (yp == 2) ? P2[s] : P3[s];
        const float* __restrict__ row = xb + (size_t)r * W_IN;
        #pragma unroll
        for (int t = 0; t < 6; ++t) {
            int c = xi - 2 + t;
            c = c < 0 ? 0 : c;             // upper edge never reached (xi <= 239)
            v[t] += cys * row[c];
        }
    }

    // Horizontal pass: 4 phases sharing v[].
    float a0 = 128.f * v[2];
    float a1 = 5.f*v[0] - 18.f*v[1] + 114.f*v[2] +  36.f*v[3] - 10.f*v[4] + 1.f*v[5];
    float a2 = 4.f*v[0] - 19.f*v[1] +  79.f*v[2] +  79.f*v[3] - 19.f*v[4] + 4.f*v[5];
    float a3 = 1.f*v[0] - 10.f*v[1] +  36.f*v[2] + 114.f*v[3] - 18.f*v[4] + 5.f*v[5];

    const float k = 1.f / 16384.f;
    float4 o;
    o.x = fminf(fmaxf(floorf((a0 + 8192.f) * k), 0.f), 255.f);
    o.y = fminf(fmaxf(floorf((a1 + 8192.f) * k), 0.f), 255.f);
    o.z = fminf(fmaxf(floorf((a2 + 8192.f) * k), 0.f), 255.f);
    o.w = fminf(fmaxf(floorf((a3 + 8192.f) * k), 0.f), 255.f);

    float* __restrict__ op = out + ((size_t)bc * H_OUT + yo) * W_OUT + 4 * tx;
    *reinterpret_cast<float4*>(op) = o;
}

extern "C" void kernel_launch(void* const* d_in, const int* in_sizes, int n_in,
                              void* d_out, int out_size, void* d_ws, size_t ws_size,
                              hipStream_t stream)
{
    const float* x = (const float*)d_in[0];
    float* out = (float*)d_out;

    dim3 block(64, 4, 1);
    dim3 grid(4 /* ceil(240/64) */, H_OUT / 4, N_BC);
    hipLaunchKernelGGL(vtm_down_kernel, grid, block, 0, stream, x, out);
}

// Round 4
// 241.331 us; speedup vs baseline: 1.0538x; 1.0538x over previous
//
#include <hip/hip_runtime.h>

// VTM downsampler, scale 2.0 (which, per the reference's phase arithmetic,
// maps output col/row i to input position i/4 with 4 sub-phases 0/4/8/12 of
// the 16-phase table; all other phases unreachable; reachable phases are zero
// outside taps 3..8 -> 6-tap window at offsets -2..+3).
//
// Exactness: integer-valued fp32 inputs, integer coeffs, |partial| < 2^24 =>
// fp32 is exact integer arithmetic; pass order commutes; trunc() identity;
// final (a+8192)*2^-14 exact; floorf == jnp.floor. (absmax=0.0 in round 1.)
//
// Structure: one thread <-> one (xi, yi) integer-position pair -> computes a
// 4x4 output block from one 6x6 input window. Window staged via LDS per
// block: 9 rows x 69 cols (2.6 KB). Store-bound: 50 MB nontemporal.

#define H_IN   1080
#define W_IN   1920
#define H_OUT  540
#define W_OUT  960
#define N_BC   24          // 8 batches * 3 channels
#define XI_N   (W_OUT/4)   // 240 integer column positions
#define YI_N   (H_OUT/4)   // 135 integer row positions

#define TILE_R 9           // rows 4*by-2 .. 4*by+6
#define TILE_C 69          // cols 64*bx-2 .. 64*bx+66
#define TILE_CP 72         // padded row stride

typedef float v4f __attribute__((ext_vector_type(4)));  // native vector for nontemporal store

__global__ __launch_bounds__(256)
void vtm_down_kernel(const float* __restrict__ x, float* __restrict__ out)
{
    const int lane = threadIdx.x;          // 0..63
    const int ty   = threadIdx.y;          // 0..3
    const int bx   = blockIdx.x;           // 0..3   (xi tile)
    const int by   = blockIdx.y;           // 0..33  (yi tile)
    const int bc   = blockIdx.z;           // 0..23

    const float* __restrict__ xb = x + (size_t)bc * (H_IN * W_IN);

    __shared__ float tile[TILE_R][TILE_CP];

    // ---- stage 9x69 input window ----
    const int r0 = 4 * by - 2;             // may be -2..-1 at top edge
    const int c0 = 64 * bx - 2;            // may be -2..-1 at left edge
    #pragma unroll
    for (int r = ty; r < TILE_R; r += 4) {
        int gr = r0 + r; gr = gr < 0 ? 0 : gr;              // max 138 < 1080: no high clamp
        const float* __restrict__ row = xb + (size_t)gr * W_IN;
        for (int c = lane; c < TILE_C; c += 64) {
            int gc = c0 + c; gc = gc < 0 ? 0 : gc;          // max 258 < 1920: no high clamp
            tile[r][c] = row[gc];
        }
    }
    __syncthreads();

    const int xi = bx * 64 + lane;
    const int yi = by * 4 + ty;
    if (xi >= XI_N || yi >= YI_N) return;

    // Vertical coefficients, phases 1..3 (phase 0 is pure copy of s=2 row).
    const float C1[6] = {5.f, -18.f, 114.f, 36.f, -10.f, 1.f};
    const float C2[6] = {4.f, -19.f,  79.f, 79.f, -19.f, 4.f};
    const float C3[6] = {1.f, -10.f,  36.f,114.f, -18.f, 5.f};

    float v0[6], v1[6] = {0,0,0,0,0,0}, v2[6] = {0,0,0,0,0,0}, v3[6] = {0,0,0,0,0,0};
    #pragma unroll
    for (int s = 0; s < 6; ++s) {
        float w[6];
        #pragma unroll
        for (int t = 0; t < 6; ++t) w[t] = tile[ty + s][lane + t];
        if (s == 2) {
            #pragma unroll
            for (int t = 0; t < 6; ++t) v0[t] = 128.f * w[t];
        }
        #pragma unroll
        for (int t = 0; t < 6; ++t) {
            v1[t] = fmaf(C1[s], w[t], v1[t]);
            v2[t] = fmaf(C2[s], w[t], v2[t]);
            v3[t] = fmaf(C3[s], w[t], v3[t]);
        }
    }

    // ---- horizontal phases + normalize + store 4 rows of float4 ----
    const float k = 1.f / 16384.f;
    float* __restrict__ ob = out + ((size_t)bc * H_OUT + 4 * yi) * W_OUT + 4 * xi;

    #pragma unroll
    for (int p = 0; p < 4; ++p) {
        const float* v = (p == 0) ? v0 : (p == 1) ? v1 : (p == 2) ? v2 : v3;
        float a0 = 128.f * v[2];
        float a1 = 5.f*v[0] - 18.f*v[1] + 114.f*v[2] +  36.f*v[3] - 10.f*v[4] + 1.f*v[5];
        float a2 = 4.f*v[0] - 19.f*v[1] +  79.f*v[2] +  79.f*v[3] - 19.f*v[4] + 4.f*v[5];
        float a3 = 1.f*v[0] - 10.f*v[1] +  36.f*v[2] + 114.f*v[3] - 18.f*v[4] + 5.f*v[5];

        v4f o;
        o.x = fminf(fmaxf(floorf((a0 + 8192.f) * k), 0.f), 255.f);
        o.y = fminf(fmaxf(floorf((a1 + 8192.f) * k), 0.f), 255.f);
        o.z = fminf(fmaxf(floorf((a2 + 8192.f) * k), 0.f), 255.f);
        o.w = fminf(fmaxf(floorf((a3 + 8192.f) * k), 0.f), 255.f);
        __builtin_nontemporal_store(o, reinterpret_cast<v4f*>(ob + (size_t)p * W_OUT));
    }
}

extern "C" void kernel_launch(void* const* d_in, const int* in_sizes, int n_in,
                              void* d_out, int out_size, void* d_ws, size_t ws_size,
                              hipStream_t stream)
{
    const float* x = (const float*)d_in[0];
    float* out = (float*)d_out;

    dim3 block(64, 4, 1);
    dim3 grid(4 /* ceil(240/64) */, 34 /* ceil(135/4) */, N_BC);
    hipLaunchKernelGGL(vtm_down_kernel, grid, block, 0, stream, x, out);
}